// Round 4
// baseline (802.754 us; speedup 1.0000x reference)
//
#include <hip/hip_runtime.h>
#include <hip/hip_bf16.h>

#define NN 100000      // N_SRC == N_DST
#define EDGES 500000
#define DD 128
#define NBKT 196       // buckets of 512 nodes (100000/512 -> 196)
#define SLACK 3584     // per-bucket record capacity (mean 2551, sigma ~50 -> 20 sigma margin)
#define CHUNK 4096     // edges per bin_scatter block
#define BPD ((EDGES + CHUNK - 1) / CHUNK)   // 123

// ---- blocked ("fragment-native") layout for all bf16 H matrices ----
// shorts offset(row, colElem) = (row>>4)*2048 + (colElem>>5)*512
//                             + ((colElem>>3)&3)*128 + (row&15)*8 + (colElem&7)
// => an MFMA A-fragment load (16 rows x 16B at k-slice ks) is
//    base + rt*2048 + ks*512 + lane*8  == 64 lanes x 16B CONTIGUOUS (8 full lines).
// NN % 16 == 0, so no padding (6250 row-tiles x 4KB).

typedef short bf16x8 __attribute__((ext_vector_type(8)));
typedef float f32x4  __attribute__((ext_vector_type(4)));
typedef float f32x2  __attribute__((ext_vector_type(2)));

__device__ __forceinline__ unsigned short f2bf(float f) {
    unsigned u = __float_as_uint(f);
    u += 0x7fffu + ((u >> 16) & 1u);      // round-to-nearest-even (no NaN inputs here)
    return (unsigned short)(u >> 16);
}

// ---------------- fp32 -> bf16 conversion, blocked output layout ----------------
// thread t: row = t>>4, sl = t&15 (one 16B output granule = 8 elems).
// Reads: 16 lanes cover one full 512B row -> fully coalesced.
// Writes: 16B granules scattered within the row-tile (L2 write-combined; every
// tile is fully written by the grid).
__global__ void f2bx_kernel(const float* __restrict__ a, const float* __restrict__ b,
                            unsigned short* __restrict__ oa, unsigned short* __restrict__ ob) {
    const float* in = blockIdx.y ? b : a;
    unsigned short* out = blockIdx.y ? ob : oa;
    int t = blockIdx.x * 256 + threadIdx.x;          // t < NN*16
    int row = t >> 4, sl = t & 15;
    const float4* src = (const float4*)in + row * 32 + sl * 2;
    float4 v0 = src[0], v1 = src[1];
    uint4 o;
    o.x = (unsigned)f2bf(v0.x) | ((unsigned)f2bf(v0.y) << 16);
    o.y = (unsigned)f2bf(v0.z) | ((unsigned)f2bf(v0.w) << 16);
    o.z = (unsigned)f2bf(v1.x) | ((unsigned)f2bf(v1.y) << 16);
    o.w = (unsigned)f2bf(v1.z) | ((unsigned)f2bf(v1.w) << 16);
    int boff = (row >> 4) * 2048 + (sl >> 2) * 512 + (sl & 3) * 128 + (row & 15) * 8;
    *(uint4*)(out + boff) = o;
}

__global__ void f2bw_kernel(const float* __restrict__ w0, const float* __restrict__ w1,
                            const float* __restrict__ w2, const float* __restrict__ w3,
                            unsigned short* __restrict__ o0, unsigned short* __restrict__ o1,
                            unsigned short* __restrict__ o2, unsigned short* __restrict__ o3) {
    const float* in; unsigned short* out;
    switch (blockIdx.y) {
        case 0: in = w0; out = o0; break;
        case 1: in = w1; out = o1; break;
        case 2: in = w2; out = o2; break;
        default: in = w3; out = o3; break;
    }
    int i = blockIdx.x * 256 + threadIdx.x;          // i < 2*DD*DD/4 = 8192
    float4 v = ((const float4*)in)[i];
    ushort4 o;
    o.x = f2bf(v.x); o.y = f2bf(v.y); o.z = f2bf(v.z); o.w = f2bf(v.w);
    ((ushort4*)out)[i] = o;
}

// ---------------- pass 1: bucket-binned edge scatter (LDS multisplit) ----------------
__global__ __launch_bounds__(256) void bin_scatter_kernel(
    const int* __restrict__ e_src, const int* __restrict__ e_dst,
    int* __restrict__ gcnt,              // [2*256], zero-initialized
    unsigned* __restrict__ recbin)       // [2 * NBKT * SLACK]
{
    const int dir = blockIdx.y;
    const int t = threadIdx.x;
    const int c0 = blockIdx.x * CHUNK;
    const int nvalid = min(CHUNK, EDGES - c0);
    const int* __restrict__ TGT = dir ? e_src : e_dst;
    const int* __restrict__ PAY = dir ? e_dst : e_src;

    __shared__ int hist[256];
    __shared__ int lbase[256];
    __shared__ int lofs[256];
    __shared__ int scanA[256], scanB[256];
    __shared__ int laddr[CHUNK];
    __shared__ unsigned lrec[CHUNK];

    hist[t] = 0;
    __syncthreads();

    int myb[16], myslot[16];
    unsigned myrec[16];
    #pragma unroll
    for (int j = 0; j < 16; ++j) {
        int e = c0 + j * 256 + t;
        myb[j] = -1;
        if (e < EDGES) {
            int tgt = TGT[e], pay = PAY[e];
            int b = tgt >> 9;
            myb[j] = b;
            myrec[j] = ((unsigned)pay << 9) | (unsigned)(tgt & 511);
            myslot[j] = atomicAdd(&hist[b], 1);
        }
    }
    __syncthreads();
    int cnt = hist[t];
    lbase[t] = (cnt > 0) ? atomicAdd(&gcnt[dir * 256 + t], cnt) : 0;
    scanA[t] = cnt;
    __syncthreads();
    int* pa = scanA; int* pb = scanB;
    for (int d = 1; d < 256; d <<= 1) {
        pb[t] = pa[t] + (t >= d ? pa[t - d] : 0);
        __syncthreads();
        int* tmp = pa; pa = pb; pb = tmp;
    }
    lofs[t] = pa[t] - cnt;                 // exclusive scan
    __syncthreads();
    #pragma unroll
    for (int j = 0; j < 16; ++j) {
        if (myb[j] >= 0) {
            int b = myb[j];
            int pos = lofs[b] + myslot[j];
            int g = lbase[b] + myslot[j];
            lrec[pos] = myrec[j];
            laddr[pos] = (g < SLACK) ? (b * SLACK + g) : -1;   // overflow guard (won't trigger)
        }
    }
    __syncthreads();
    unsigned* __restrict__ out = recbin + (size_t)dir * NBKT * SLACK;
    #pragma unroll
    for (int j = 0; j < 16; ++j) {
        int i = j * 256 + t;
        if (i < nvalid) {
            int a = laddr[i];
            if (a >= 0) out[a] = lrec[i];  // bucket-sorted -> near-coalesced runs
        }
    }
}

// ---------------- pass 2: tiny scan of bucket counts -> csr bases ----------------
__global__ void bucket_scan_kernel(const int* __restrict__ gcnt, int* __restrict__ csr_base) {
    int t = threadIdx.x;
    __shared__ int A[256], B[256];
    for (int dir = 0; dir < 2; ++dir) {
        int c = (t < NBKT) ? min(gcnt[dir * 256 + t], SLACK) : 0;
        A[t] = c;
        __syncthreads();
        int* pa = A; int* pb = B;
        for (int d = 1; d < 256; d <<= 1) {
            pb[t] = pa[t] + (t >= d ? pa[t - d] : 0);
            __syncthreads();
            int* tmp = pa; pa = pb; pb = tmp;
        }
        if (t < NBKT) csr_base[dir * 200 + t] = pa[t] - c;
        if (t == 0)   csr_base[dir * 200 + NBKT] = pa[255];   // total (== EDGES)
        __syncthreads();
    }
}

// ---------------- pass 3: per-bucket fine placement + rp + invdeg ----------------
__global__ __launch_bounds__(256) void fine_place_kernel(
    const unsigned* __restrict__ recbin, const int* __restrict__ gcnt,
    const int* __restrict__ csr_base,
    int* __restrict__ rp_dst, int* __restrict__ rp_src,
    float* __restrict__ inv_dst, float* __restrict__ inv_src,
    int* __restrict__ csr_dst, int* __restrict__ csr_src)
{
    const int dir = blockIdx.y;
    const int bkt = blockIdx.x;
    const int t = threadIdx.x;
    int*   __restrict__ rp  = dir ? rp_src  : rp_dst;
    float* __restrict__ inv = dir ? inv_src : inv_dst;
    int*   __restrict__ csr = dir ? csr_src : csr_dst;
    const unsigned* __restrict__ recs = recbin + ((size_t)dir * NBKT + bkt) * SLACK;
    const int cnt = min(gcnt[dir * 256 + bkt], SLACK);
    const int cbase = csr_base[dir * 200 + bkt];
    const int n0 = bkt * 512;

    __shared__ int deg[512];
    __shared__ int sA[512], sB[512];
    __shared__ int cur[512];
    deg[t] = 0; deg[t + 256] = 0;
    __syncthreads();
    for (int i = t; i < cnt; i += 256)
        atomicAdd(&deg[recs[i] & 511u], 1);
    __syncthreads();
    sA[t] = deg[t]; sA[t + 256] = deg[t + 256];
    __syncthreads();
    int* pa = sA; int* pb = sB;
    for (int d = 1; d < 512; d <<= 1) {
        pb[t]       = pa[t]       + (t >= d           ? pa[t - d]       : 0);
        pb[t + 256] = pa[t + 256] + ((t + 256) >= d   ? pa[t + 256 - d] : 0);
        __syncthreads();
        int* tmp = pa; pa = pb; pb = tmp;
    }
    #pragma unroll
    for (int k = 0; k < 2; ++k) {
        int i = t + k * 256;
        int off = pa[i] - deg[i];          // exclusive
        cur[i] = off;
        int node = n0 + i;
        if (node < NN) {
            rp[node] = cbase + off;        // coalesced rp write
            inv[node] = 1.0f / (float)max(deg[i], 1);
        }
    }
    if (bkt == NBKT - 1 && t == 0) rp[NN] = csr_base[dir * 200 + NBKT];
    __syncthreads();
    for (int i = t; i < cnt; i += 256) {
        unsigned r = recs[i];
        int p = atomicAdd(&cur[r & 511u], 1);
        csr[cbase + p] = (int)(r >> 9);    // scattered 4B stores within ~10KB window
    }
}

// ---------------- mean aggregation v4 (blocked layout in & out) ----------------
// wave = 4 nodes, 16 lanes per node, 16B per lane; all csr + all row gathers
// issued flat (3 serialized memory phases per wave regardless of degree).
// Gathers remain one 16B granule per lane (random rows -> layout-neutral).
__global__ __launch_bounds__(256) void aggregate4_kernel(
    const unsigned short* __restrict__ h0, const int* __restrict__ rp0,
    const int* __restrict__ csr0, unsigned short* __restrict__ ag0,
    const unsigned short* __restrict__ h1, const int* __restrict__ rp1,
    const int* __restrict__ csr1, unsigned short* __restrict__ ag1)
{
    const int dir = blockIdx.y;
    const unsigned short* __restrict__ h = dir ? h1 : h0;
    const int* __restrict__ rp   = dir ? rp1 : rp0;
    const int* __restrict__ csr  = dir ? csr1 : csr0;
    unsigned short* __restrict__ agg = dir ? ag1 : ag0;

    const int t  = blockIdx.x * 256 + threadIdx.x;
    const int g  = t >> 4;          // node id (grid sized exactly: NN*16 threads)
    const int sl = t & 15;          // which 16B k-granule of the 256B row

    const int beg = rp[g], end = rp[g + 1];
    const int koff = (sl >> 2) * 512 + (sl & 3) * 128;   // blocked k-slice offset (shorts)
    const unsigned short* __restrict__ hp = h + koff;

    f32x2 acc[4];
    #pragma unroll
    for (int k = 0; k < 4; ++k) acc[k] = (f32x2){0.f, 0.f};

    // phase 2: all csr indices at once (predicated, independent)
    int cidx[8];
    #pragma unroll
    for (int j = 0; j < 8; ++j)
        cidx[j] = (beg + j < end) ? csr[beg + j] : -1;

    // phase 3: all row gathers at once (independent dwordx4 loads)
    bf16x8 v[8];
    #pragma unroll
    for (int j = 0; j < 8; ++j)
        if (cidx[j] >= 0) {
            int c = cidx[j];
            v[j] = *(const bf16x8*)(hp + (c >> 4) * 2048 + (c & 15) * 8);
        }

    #pragma unroll
    for (int j = 0; j < 8; ++j) {
        if (cidx[j] >= 0) {
            const unsigned* pu = (const unsigned*)&v[j];
            #pragma unroll
            for (int k = 0; k < 4; ++k) {
                unsigned u = pu[k];
                acc[k] += (f32x2){__uint_as_float(u << 16),
                                  __uint_as_float(u & 0xffff0000u)};
            }
        }
    }

    // rare tail: deg > 8 (~7% of nodes)
    for (int i = beg + 8; i < end; ++i) {
        int c = csr[i];
        bf16x8 wv = *(const bf16x8*)(hp + (c >> 4) * 2048 + (c & 15) * 8);
        const unsigned* pu = (const unsigned*)&wv;
        #pragma unroll
        for (int k = 0; k < 4; ++k) {
            unsigned u = pu[k];
            acc[k] += (f32x2){__uint_as_float(u << 16),
                              __uint_as_float(u & 0xffff0000u)};
        }
    }

    const float sc = 1.0f / (float)max(end - beg, 1);
    uint4 ov;
    ov.x = (unsigned)f2bf(acc[0].x * sc) | ((unsigned)f2bf(acc[0].y * sc) << 16);
    ov.y = (unsigned)f2bf(acc[1].x * sc) | ((unsigned)f2bf(acc[1].y * sc) << 16);
    ov.z = (unsigned)f2bf(acc[2].x * sc) | ((unsigned)f2bf(acc[2].y * sc) << 16);
    ov.w = (unsigned)f2bf(acc[3].x * sc) | ((unsigned)f2bf(acc[3].y * sc) << 16);
    *(uint4*)(agg + (g >> 4) * 2048 + koff + (g & 15) * 8) = ov;   // blocked store
}

// ---------------- MFMA GEMM v8: v5 structure + fragment-native A layout ----------------
// out = relu([Hself|Hagg] @ [Wself|Wneigh]^T + b), bf16 in, fp32 acc.
// Post-mortem chain: v5 62.5us / v6 75us / v7 95us all show gather-granularity
// ~2.2TB/s cap: A-fragment loads were 16 x 64B segments per wave-instr.
// v8 stores H in the blocked layout so each A-fragment load is 64 lanes x 16B
// CONTIGUOUS (8 full 128B lines) -> per-txn bytes double, latency cap lifts.
// Structure = v5 (best measured): 391x2 blocks, 8 waves, M=256 x N=128, 64KB
// weight LDS, 2 blocks/CU, 1-deep A prefetch, B-frags hoisted (4 reads/ks).
// Not in-place (caller ping-pongs) -> no pre-epilogue barrier.
__global__ __launch_bounds__(512, 4) void mfma_gemm8_kernel(
    const unsigned short* __restrict__ Hs0, const unsigned short* __restrict__ Ha0,
    const unsigned short* __restrict__ Ws0, const unsigned short* __restrict__ Wn0,
    const float* __restrict__ bias0, float* __restrict__ outF0, unsigned short* __restrict__ outB0,
    const unsigned short* __restrict__ Hs1, const unsigned short* __restrict__ Ha1,
    const unsigned short* __restrict__ Ws1, const unsigned short* __restrict__ Wn1,
    const float* __restrict__ bias1, float* __restrict__ outF1, unsigned short* __restrict__ outB1,
    int M)
{
    const int dir = blockIdx.y;
    const unsigned short* __restrict__ Hself = dir ? Hs1 : Hs0;
    const unsigned short* __restrict__ Hagg  = dir ? Ha1 : Ha0;
    const unsigned short* __restrict__ Wself = dir ? Ws1 : Ws0;
    const unsigned short* __restrict__ Wneigh= dir ? Wn1 : Wn0;
    const float* __restrict__ bias = dir ? bias1 : bias0;
    float* __restrict__ outF = dir ? outF1 : outF0;
    unsigned short* __restrict__ outB = dir ? outB1 : outB0;

    __shared__ __align__(16) unsigned short sW[128 * 256];  // fused weights, swizzled (64 KB)
    const int tid  = threadIdx.x;
    const int lane = tid & 63;
    const int w    = tid >> 6;                // 0..7
    const int row0 = blockIdx.x * 256;

    #pragma unroll
    for (int i = 0; i < 8; ++i) {             // stage fused weights (swizzled): 128B/thread
        int q = i * 512 + tid;                // 0..4095
        int n = q >> 5, c = q & 31;
        const unsigned short* src = (c < 16) ? (Wself + n * 128 + c * 8)
                                             : (Wneigh + n * 128 + (c - 16) * 8);
        int d = n * 256 + (c & 24) * 8 + (((c ^ n) & 7) * 8);
        *(uint4*)(sW + d) = *(const uint4*)src;
    }

    const int mbase = (w >> 1) * 64;          // 0,64,128,192
    const int nbase = (w & 1) * 64;           // 0,64
    const int l15 = lane & 15;
    const int l4  = lane >> 4;
    const int MT  = M >> 4;                   // 6250 row-tiles

    // blocked A offsets (shorts): rt*2048 + lane*8 ; k-slice adds ks*512
    int aoff[4];
    #pragma unroll
    for (int mt = 0; mt < 4; ++mt) {
        int rt = ((row0 + mbase) >> 4) + mt;
        if (rt >= MT) rt = MT - 1;            // tail clamp (valid data, results discarded)
        aoff[mt] = rt * 2048 + lane * 8;
    }

    f32x4 acc[4][4];
    #pragma unroll
    for (int mt = 0; mt < 4; ++mt)
        #pragma unroll
        for (int nt = 0; nt < 4; ++nt) acc[mt][nt] = (f32x4){0.f, 0.f, 0.f, 0.f};

    __syncthreads();   // weights ready

    bf16x8 a_cur[4], a_nxt[4];
    #pragma unroll
    for (int mt = 0; mt < 4; ++mt) a_cur[mt] = *(const bf16x8*)(Hself + aoff[mt]);

    #pragma unroll
    for (int ks = 0; ks < 8; ++ks) {
        if (ks < 7) {
            const int ks1 = ks + 1;
            const int col = (ks1 & 3) * 512;    // blocked k-slice offset (shorts)
            const unsigned short* __restrict__ base = (ks1 < 4) ? Hself : Hagg;  // compile-time
            #pragma unroll
            for (int mt = 0; mt < 4; ++mt)
                a_nxt[mt] = *(const bf16x8*)(base + aoff[mt] + col);
        }
        const int c = ks * 4 + l4;
        bf16x8 b[4];                            // shared across all mt (4 LDS reads/ks)
        #pragma unroll
        for (int nt = 0; nt < 4; ++nt) {
            int n = nbase + nt * 16 + l15;
            b[nt] = *(const bf16x8*)(sW + n * 256 + (c & 24) * 8 + (((c ^ n) & 7) * 8));
        }
        #pragma unroll
        for (int mt = 0; mt < 4; ++mt) {
            acc[mt][0] = __builtin_amdgcn_mfma_f32_16x16x32_bf16(a_cur[mt], b[0], acc[mt][0], 0, 0, 0);
            acc[mt][1] = __builtin_amdgcn_mfma_f32_16x16x32_bf16(a_cur[mt], b[1], acc[mt][1], 0, 0, 0);
            acc[mt][2] = __builtin_amdgcn_mfma_f32_16x16x32_bf16(a_cur[mt], b[2], acc[mt][2], 0, 0, 0);
            acc[mt][3] = __builtin_amdgcn_mfma_f32_16x16x32_bf16(a_cur[mt], b[3], acc[mt][3], 0, 0, 0);
        }
        #pragma unroll
        for (int mt = 0; mt < 4; ++mt) a_cur[mt] = a_nxt[mt];
    }

    // epilogue (no barrier: not in-place, LDS untouched)
    #pragma unroll
    for (int nt = 0; nt < 4; ++nt) {
        int col = nbase + nt * 16 + l15;
        float bj = bias[col];
        #pragma unroll
        for (int mt = 0; mt < 4; ++mt) {
            #pragma unroll
            for (int r = 0; r < 4; ++r) {
                int grow = row0 + mbase + mt * 16 + l4 * 4 + r;
                if (grow < M) {
                    float v = fmaxf(acc[mt][nt][r] + bj, 0.f);
                    if (outF) {
                        outF[(size_t)grow * 128 + col] = v;          // final out: row-major f32
                    } else {
                        int bo = (grow >> 4) * 2048 + (col >> 5) * 512
                               + ((col >> 3) & 3) * 128 + (grow & 15) * 8 + (col & 7);
                        outB[bo] = f2bf(v);                          // blocked bf16 (layer 0)
                    }
                }
            }
        }
    }
}

extern "C" void kernel_launch(void* const* d_in, const int* in_sizes, int n_in,
                              void* d_out, int out_size, void* d_ws, size_t ws_size,
                              hipStream_t stream) {
    const float* x_src        = (const float*)d_in[0];
    const float* x_dst        = (const float*)d_in[1];
    const int*   e_src        = (const int*)d_in[2];
    const int*   e_dst        = (const int*)d_in[3];
    const float* W_ship_self  = (const float*)d_in[4];
    const float* W_ship_neigh = (const float*)d_in[5];
    const float* b_ship       = (const float*)d_in[6];
    const float* W_rev_self   = (const float*)d_in[7];
    const float* W_rev_neigh  = (const float*)d_in[8];
    const float* b_rev        = (const float*)d_in[9];
    float* out = (float*)d_out;

    char* ws = (char*)d_ws;
    size_t off = 0;
    auto alloc = [&](size_t bytes) {
        char* p = ws + off;
        off = (off + bytes + 255) & ~(size_t)255;
        return p;
    };
    unsigned short* xs_bf  = (unsigned short*)alloc((size_t)NN * DD * 2);   // blocked
    unsigned short* xd_bf  = (unsigned short*)alloc((size_t)NN * DD * 2);   // blocked
    unsigned short* xs2_bf = (unsigned short*)alloc((size_t)NN * DD * 2);   // blocked (layer-0 out)
    unsigned short* xd2_bf = (unsigned short*)alloc((size_t)NN * DD * 2);   // blocked
    unsigned short* agg1   = (unsigned short*)alloc((size_t)NN * DD * 2);   // blocked
    unsigned short* agg2   = (unsigned short*)alloc((size_t)NN * DD * 2);   // blocked
    unsigned short* Wss_bf = (unsigned short*)alloc(2 * DD * DD * 2);
    unsigned short* Wsn_bf = (unsigned short*)alloc(2 * DD * DD * 2);
    unsigned short* Wrs_bf = (unsigned short*)alloc(2 * DD * DD * 2);
    unsigned short* Wrn_bf = (unsigned short*)alloc(2 * DD * DD * 2);
    int* gcnt = (int*)alloc(2 * 256 * 4);
    int* csr_base = (int*)alloc(2 * 200 * 4);
    unsigned* recbin = (unsigned*)alloc((size_t)2 * NBKT * SLACK * 4);
    int* rp_dst = (int*)alloc((NN + 1) * 4);
    int* rp_src = (int*)alloc((NN + 1) * 4);
    float* inv_dst = (float*)alloc(NN * 4);
    float* inv_src = (float*)alloc(NN * 4);
    int* csr_dst = (int*)alloc(EDGES * 4);
    int* csr_src = (int*)alloc(EDGES * 4);
    (void)ws_size; (void)in_sizes; (void)n_in; (void)out_size;

    hipMemsetAsync(gcnt, 0, 2 * 256 * 4, stream);

    f2bx_kernel<<<dim3(NN * 16 / 256, 2), 256, 0, stream>>>(x_src, x_dst, xs_bf, xd_bf);
    f2bw_kernel<<<dim3(32, 4), 256, 0, stream>>>(W_ship_self, W_ship_neigh, W_rev_self, W_rev_neigh,
                                                 Wss_bf, Wsn_bf, Wrs_bf, Wrn_bf);

    bin_scatter_kernel<<<dim3(BPD, 2), 256, 0, stream>>>(e_src, e_dst, gcnt, recbin);
    bucket_scan_kernel<<<1, 256, 0, stream>>>(gcnt, csr_base);
    fine_place_kernel<<<dim3(NBKT, 2), 256, 0, stream>>>(recbin, gcnt, csr_base,
        rp_dst, rp_src, inv_dst, inv_src, csr_dst, csr_src);

    float* out_s = out;                       // h_s final
    float* out_d = out + (size_t)NN * DD;     // h_d final
    const int gemm_grid = (NN + 255) / 256;   // 391 (M=256 per block)
    const int agg_grid  = NN * 16 / 256;      // 6250 (16 lanes per node)

    for (int l = 0; l < 2; ++l) {
        const unsigned short* hs = l ? xs2_bf : xs_bf;   // current h_s (blocked)
        const unsigned short* hd = l ? xd2_bf : xd_bf;   // current h_d (blocked)
        // dir0: agg1 = mean h_s by dst ; dir1: agg2 = mean h_d by src
        aggregate4_kernel<<<dim3(agg_grid, 2), 256, 0, stream>>>(
            hs, rp_dst, csr_dst, agg1,
            hd, rp_src, csr_src, agg2);
        // dir0: new_d = relu(h_d@Wss^T + agg1@Wsn^T + b_ship)
        // dir1: new_s = relu(h_s@Wrs^T + agg2@Wrn^T + b_rev)
        mfma_gemm8_kernel<<<dim3(gemm_grid, 2), 512, 0, stream>>>(
            hd, agg1, Wss_bf + l * DD * DD, Wsn_bf + l * DD * DD, b_ship + l * DD,
            l ? out_d : nullptr, l ? nullptr : xd2_bf,
            hs, agg2, Wrs_bf + l * DD * DD, Wrn_bf + l * DD * DD, b_rev + l * DD,
            l ? out_s : nullptr, l ? nullptr : xs2_bf,
            NN);
    }
}

// Round 5
// 420.032 us; speedup vs baseline: 1.9112x; 1.9112x over previous
//
#include <hip/hip_runtime.h>
#include <hip/hip_bf16.h>

#define NN 100000      // N_SRC == N_DST
#define EDGES 500000
#define DD 128
#define NBKT 196       // buckets of 512 nodes (100000/512 -> 196)
#define SLACK 3584     // per-bucket record capacity (mean 2551, sigma ~50 -> 20 sigma margin)
#define CHUNK 4096     // edges per bin_scatter block
#define BPD ((EDGES + CHUNK - 1) / CHUNK)   // 123

// ---- dual layouts for bf16 H matrices ----
// ROW-major  (aggregate gather source): h[row*128 + col]  -> a neighbor row is
//   256B contiguous; 16-lane gather of one row = 2 full lines, zero over-fetch.
// BLOCKED    (GEMM A source): offset(row,col) = (row>>4)*2048 + (col>>5)*512
//   + ((col>>3)&3)*128 + (row&15)*8 + (col&7)  -> an MFMA A-fragment load is
//   base + rt*2048 + ks*512 + lane*8 == 64 lanes x 16B CONTIGUOUS (8 full lines).
// Producers write both; consumers pick their native layout.

typedef short bf16x8 __attribute__((ext_vector_type(8)));
typedef float f32x4  __attribute__((ext_vector_type(4)));
typedef float f32x2  __attribute__((ext_vector_type(2)));

__device__ __forceinline__ unsigned short f2bf(float f) {
    unsigned u = __float_as_uint(f);
    u += 0x7fffu + ((u >> 16) & 1u);      // round-to-nearest-even (no NaN inputs here)
    return (unsigned short)(u >> 16);
}

// ---------------- fp32 -> bf16, writes BOTH layouts ----------------
// thread t: row = t>>4, sl = t&15 (one 16B granule = 8 elems).
__global__ void f2bx_kernel(const float* __restrict__ a, const float* __restrict__ b,
                            unsigned short* __restrict__ oaR, unsigned short* __restrict__ oaB,
                            unsigned short* __restrict__ obR, unsigned short* __restrict__ obB) {
    const float* in = blockIdx.y ? b : a;
    unsigned short* outR = blockIdx.y ? obR : oaR;
    unsigned short* outB = blockIdx.y ? obB : oaB;
    int t = blockIdx.x * 256 + threadIdx.x;          // t < NN*16
    int row = t >> 4, sl = t & 15;
    const float4* src = (const float4*)in + row * 32 + sl * 2;
    float4 v0 = src[0], v1 = src[1];
    uint4 o;
    o.x = (unsigned)f2bf(v0.x) | ((unsigned)f2bf(v0.y) << 16);
    o.y = (unsigned)f2bf(v0.z) | ((unsigned)f2bf(v0.w) << 16);
    o.z = (unsigned)f2bf(v1.x) | ((unsigned)f2bf(v1.y) << 16);
    o.w = (unsigned)f2bf(v1.z) | ((unsigned)f2bf(v1.w) << 16);
    *(uint4*)(outR + row * 128 + sl * 8) = o;        // row-major
    int boff = (row >> 4) * 2048 + (sl >> 2) * 512 + (sl & 3) * 128 + (row & 15) * 8;
    *(uint4*)(outB + boff) = o;                      // blocked (block writes whole tiles)
}

__global__ void f2bw_kernel(const float* __restrict__ w0, const float* __restrict__ w1,
                            const float* __restrict__ w2, const float* __restrict__ w3,
                            unsigned short* __restrict__ o0, unsigned short* __restrict__ o1,
                            unsigned short* __restrict__ o2, unsigned short* __restrict__ o3) {
    const float* in; unsigned short* out;
    switch (blockIdx.y) {
        case 0: in = w0; out = o0; break;
        case 1: in = w1; out = o1; break;
        case 2: in = w2; out = o2; break;
        default: in = w3; out = o3; break;
    }
    int i = blockIdx.x * 256 + threadIdx.x;          // i < 2*DD*DD/4 = 8192
    float4 v = ((const float4*)in)[i];
    ushort4 o;
    o.x = f2bf(v.x); o.y = f2bf(v.y); o.z = f2bf(v.z); o.w = f2bf(v.w);
    ((ushort4*)out)[i] = o;
}

// ---------------- pass 1: bucket-binned edge scatter (LDS multisplit) ----------------
__global__ __launch_bounds__(256) void bin_scatter_kernel(
    const int* __restrict__ e_src, const int* __restrict__ e_dst,
    int* __restrict__ gcnt,              // [2*256], zero-initialized
    unsigned* __restrict__ recbin)       // [2 * NBKT * SLACK]
{
    const int dir = blockIdx.y;
    const int t = threadIdx.x;
    const int c0 = blockIdx.x * CHUNK;
    const int nvalid = min(CHUNK, EDGES - c0);
    const int* __restrict__ TGT = dir ? e_src : e_dst;
    const int* __restrict__ PAY = dir ? e_dst : e_src;

    __shared__ int hist[256];
    __shared__ int lbase[256];
    __shared__ int lofs[256];
    __shared__ int scanA[256], scanB[256];
    __shared__ int laddr[CHUNK];
    __shared__ unsigned lrec[CHUNK];

    hist[t] = 0;
    __syncthreads();

    int myb[16], myslot[16];
    unsigned myrec[16];
    #pragma unroll
    for (int j = 0; j < 16; ++j) {
        int e = c0 + j * 256 + t;
        myb[j] = -1;
        if (e < EDGES) {
            int tgt = TGT[e], pay = PAY[e];
            int b = tgt >> 9;
            myb[j] = b;
            myrec[j] = ((unsigned)pay << 9) | (unsigned)(tgt & 511);
            myslot[j] = atomicAdd(&hist[b], 1);
        }
    }
    __syncthreads();
    int cnt = hist[t];
    lbase[t] = (cnt > 0) ? atomicAdd(&gcnt[dir * 256 + t], cnt) : 0;
    scanA[t] = cnt;
    __syncthreads();
    int* pa = scanA; int* pb = scanB;
    for (int d = 1; d < 256; d <<= 1) {
        pb[t] = pa[t] + (t >= d ? pa[t - d] : 0);
        __syncthreads();
        int* tmp = pa; pa = pb; pb = tmp;
    }
    lofs[t] = pa[t] - cnt;                 // exclusive scan
    __syncthreads();
    #pragma unroll
    for (int j = 0; j < 16; ++j) {
        if (myb[j] >= 0) {
            int b = myb[j];
            int pos = lofs[b] + myslot[j];
            int g = lbase[b] + myslot[j];
            lrec[pos] = myrec[j];
            laddr[pos] = (g < SLACK) ? (b * SLACK + g) : -1;   // overflow guard (won't trigger)
        }
    }
    __syncthreads();
    unsigned* __restrict__ out = recbin + (size_t)dir * NBKT * SLACK;
    #pragma unroll
    for (int j = 0; j < 16; ++j) {
        int i = j * 256 + t;
        if (i < nvalid) {
            int a = laddr[i];
            if (a >= 0) out[a] = lrec[i];  // bucket-sorted -> near-coalesced runs
        }
    }
}

// ---------------- pass 2: tiny scan of bucket counts -> csr bases ----------------
__global__ void bucket_scan_kernel(const int* __restrict__ gcnt, int* __restrict__ csr_base) {
    int t = threadIdx.x;
    __shared__ int A[256], B[256];
    for (int dir = 0; dir < 2; ++dir) {
        int c = (t < NBKT) ? min(gcnt[dir * 256 + t], SLACK) : 0;
        A[t] = c;
        __syncthreads();
        int* pa = A; int* pb = B;
        for (int d = 1; d < 256; d <<= 1) {
            pb[t] = pa[t] + (t >= d ? pa[t - d] : 0);
            __syncthreads();
            int* tmp = pa; pa = pb; pb = tmp;
        }
        if (t < NBKT) csr_base[dir * 200 + t] = pa[t] - c;
        if (t == 0)   csr_base[dir * 200 + NBKT] = pa[255];   // total (== EDGES)
        __syncthreads();
    }
}

// ---------------- pass 3: per-bucket fine placement + rp + invdeg ----------------
__global__ __launch_bounds__(256) void fine_place_kernel(
    const unsigned* __restrict__ recbin, const int* __restrict__ gcnt,
    const int* __restrict__ csr_base,
    int* __restrict__ rp_dst, int* __restrict__ rp_src,
    float* __restrict__ inv_dst, float* __restrict__ inv_src,
    int* __restrict__ csr_dst, int* __restrict__ csr_src)
{
    const int dir = blockIdx.y;
    const int bkt = blockIdx.x;
    const int t = threadIdx.x;
    int*   __restrict__ rp  = dir ? rp_src  : rp_dst;
    float* __restrict__ inv = dir ? inv_src : inv_dst;
    int*   __restrict__ csr = dir ? csr_src : csr_dst;
    const unsigned* __restrict__ recs = recbin + ((size_t)dir * NBKT + bkt) * SLACK;
    const int cnt = min(gcnt[dir * 256 + bkt], SLACK);
    const int cbase = csr_base[dir * 200 + bkt];
    const int n0 = bkt * 512;

    __shared__ int deg[512];
    __shared__ int sA[512], sB[512];
    __shared__ int cur[512];
    deg[t] = 0; deg[t + 256] = 0;
    __syncthreads();
    for (int i = t; i < cnt; i += 256)
        atomicAdd(&deg[recs[i] & 511u], 1);
    __syncthreads();
    sA[t] = deg[t]; sA[t + 256] = deg[t + 256];
    __syncthreads();
    int* pa = sA; int* pb = sB;
    for (int d = 1; d < 512; d <<= 1) {
        pb[t]       = pa[t]       + (t >= d           ? pa[t - d]       : 0);
        pb[t + 256] = pa[t + 256] + ((t + 256) >= d   ? pa[t + 256 - d] : 0);
        __syncthreads();
        int* tmp = pa; pa = pb; pb = tmp;
    }
    #pragma unroll
    for (int k = 0; k < 2; ++k) {
        int i = t + k * 256;
        int off = pa[i] - deg[i];          // exclusive
        cur[i] = off;
        int node = n0 + i;
        if (node < NN) {
            rp[node] = cbase + off;        // coalesced rp write
            inv[node] = 1.0f / (float)max(deg[i], 1);
        }
    }
    if (bkt == NBKT - 1 && t == 0) rp[NN] = csr_base[dir * 200 + NBKT];
    __syncthreads();
    for (int i = t; i < cnt; i += 256) {
        unsigned r = recs[i];
        int p = atomicAdd(&cur[r & 511u], 1);
        csr[cbase + p] = (int)(r >> 9);    // scattered 4B stores within ~10KB window
    }
}

// ---------------- mean aggregation v5: ROW-major gather, BLOCKED store ----------------
// wave = 4 nodes, 16 lanes per node, 16B per lane; all csr + all row gathers
// issued flat (3 serialized memory phases per wave regardless of degree).
// Gather source is row-major (16 lanes x 16B = one full 256B row, zero
// over-fetch -- agg4's blocked gather was a 7x FETCH blowup, 856MB).
// Output store is blocked (consumed only by the GEMM); each 256-thread block
// covers exactly one 16-node tile -> complete-tile writes, L2-combined.
__global__ __launch_bounds__(256) void aggregate5_kernel(
    const unsigned short* __restrict__ h0, const int* __restrict__ rp0,
    const int* __restrict__ csr0, unsigned short* __restrict__ ag0,
    const unsigned short* __restrict__ h1, const int* __restrict__ rp1,
    const int* __restrict__ csr1, unsigned short* __restrict__ ag1)
{
    const int dir = blockIdx.y;
    const unsigned short* __restrict__ h = dir ? h1 : h0;
    const int* __restrict__ rp   = dir ? rp1 : rp0;
    const int* __restrict__ csr  = dir ? csr1 : csr0;
    unsigned short* __restrict__ agg = dir ? ag1 : ag0;

    const int t  = blockIdx.x * 256 + threadIdx.x;
    const int g  = t >> 4;          // node id (grid sized exactly: NN*16 threads)
    const int sl = t & 15;          // 16B slice of the 256B row

    const int beg = rp[g], end = rp[g + 1];
    const unsigned short* __restrict__ hp = h + sl * 8;   // row-major gather base

    f32x2 acc[4];
    #pragma unroll
    for (int k = 0; k < 4; ++k) acc[k] = (f32x2){0.f, 0.f};

    // phase 2: all csr indices at once (predicated, independent)
    int cidx[8];
    #pragma unroll
    for (int j = 0; j < 8; ++j)
        cidx[j] = (beg + j < end) ? csr[beg + j] : -1;

    // phase 3: all row gathers at once (independent dwordx4 loads)
    bf16x8 v[8];
    #pragma unroll
    for (int j = 0; j < 8; ++j)
        if (cidx[j] >= 0)
            v[j] = *(const bf16x8*)(hp + (size_t)cidx[j] * DD);

    #pragma unroll
    for (int j = 0; j < 8; ++j) {
        if (cidx[j] >= 0) {
            const unsigned* pu = (const unsigned*)&v[j];
            #pragma unroll
            for (int k = 0; k < 4; ++k) {
                unsigned u = pu[k];
                acc[k] += (f32x2){__uint_as_float(u << 16),
                                  __uint_as_float(u & 0xffff0000u)};
            }
        }
    }

    // rare tail: deg > 8 (~7% of nodes)
    for (int i = beg + 8; i < end; ++i) {
        int c = csr[i];
        bf16x8 wv = *(const bf16x8*)(hp + (size_t)c * DD);
        const unsigned* pu = (const unsigned*)&wv;
        #pragma unroll
        for (int k = 0; k < 4; ++k) {
            unsigned u = pu[k];
            acc[k] += (f32x2){__uint_as_float(u << 16),
                              __uint_as_float(u & 0xffff0000u)};
        }
    }

    const float sc = 1.0f / (float)max(end - beg, 1);
    uint4 ov;
    ov.x = (unsigned)f2bf(acc[0].x * sc) | ((unsigned)f2bf(acc[0].y * sc) << 16);
    ov.y = (unsigned)f2bf(acc[1].x * sc) | ((unsigned)f2bf(acc[1].y * sc) << 16);
    ov.z = (unsigned)f2bf(acc[2].x * sc) | ((unsigned)f2bf(acc[2].y * sc) << 16);
    ov.w = (unsigned)f2bf(acc[3].x * sc) | ((unsigned)f2bf(acc[3].y * sc) << 16);
    int boff = (g >> 4) * 2048 + (sl >> 2) * 512 + (sl & 3) * 128 + (g & 15) * 8;
    *(uint4*)(agg + boff) = ov;                          // blocked store
}

// ---------------- MFMA GEMM v9: blocked-A (v8) + dual-layout epilogue ----------------
// out = relu([Hself|Hagg] @ [Wself|Wneigh]^T + b), bf16 in, fp32 acc.
// A-loads from BLOCKED layout: 64 lanes x 16B contiguous per fragment.
// Layer 0 (outF==null): writes BOTH row-major bf16 (next layer's aggregate
// gather) and blocked bf16 (next layer's GEMM A) -- IN PLACE over the inputs:
// each wave reads only its own 64 rows' fragments, all reads complete (values
// consumed by MFMA) before its epilogue stores in program order; rows are
// partitioned across waves/blocks, tail-clamp reads are discarded. dir0 touches
// only xd*/agg1, dir1 only xs*/agg2. Layer 1: f32 row-major final out.
__global__ __launch_bounds__(512, 4) void mfma_gemm9_kernel(
    const unsigned short* __restrict__ Hs0, const unsigned short* __restrict__ Ha0,
    const unsigned short* __restrict__ Ws0, const unsigned short* __restrict__ Wn0,
    const float* __restrict__ bias0, float* __restrict__ outF0,
    unsigned short* __restrict__ outR0, unsigned short* __restrict__ outB0,
    const unsigned short* __restrict__ Hs1, const unsigned short* __restrict__ Ha1,
    const unsigned short* __restrict__ Ws1, const unsigned short* __restrict__ Wn1,
    const float* __restrict__ bias1, float* __restrict__ outF1,
    unsigned short* __restrict__ outR1, unsigned short* __restrict__ outB1,
    int M)
{
    const int dir = blockIdx.y;
    const unsigned short* __restrict__ Hself = dir ? Hs1 : Hs0;
    const unsigned short* __restrict__ Hagg  = dir ? Ha1 : Ha0;
    const unsigned short* __restrict__ Wself = dir ? Ws1 : Ws0;
    const unsigned short* __restrict__ Wneigh= dir ? Wn1 : Wn0;
    const float* __restrict__ bias = dir ? bias1 : bias0;
    float* __restrict__ outF = dir ? outF1 : outF0;
    unsigned short* __restrict__ outR = dir ? outR1 : outR0;
    unsigned short* __restrict__ outB = dir ? outB1 : outB0;

    __shared__ __align__(16) unsigned short sW[128 * 256];  // fused weights, swizzled (64 KB)
    const int tid  = threadIdx.x;
    const int lane = tid & 63;
    const int w    = tid >> 6;                // 0..7
    const int row0 = blockIdx.x * 256;

    #pragma unroll
    for (int i = 0; i < 8; ++i) {             // stage fused weights (swizzled): 128B/thread
        int q = i * 512 + tid;                // 0..4095
        int n = q >> 5, c = q & 31;
        const unsigned short* src = (c < 16) ? (Wself + n * 128 + c * 8)
                                             : (Wneigh + n * 128 + (c - 16) * 8);
        int d = n * 256 + (c & 24) * 8 + (((c ^ n) & 7) * 8);
        *(uint4*)(sW + d) = *(const uint4*)src;
    }

    const int mbase = (w >> 1) * 64;          // 0,64,128,192
    const int nbase = (w & 1) * 64;           // 0,64
    const int l15 = lane & 15;
    const int l4  = lane >> 4;
    const int MT  = M >> 4;                   // 6250 row-tiles

    // blocked A offsets (shorts): rt*2048 + lane*8 ; k-slice adds ks*512
    int aoff[4];
    #pragma unroll
    for (int mt = 0; mt < 4; ++mt) {
        int rt = ((row0 + mbase) >> 4) + mt;
        if (rt >= MT) rt = MT - 1;            // tail clamp (valid data, results discarded)
        aoff[mt] = rt * 2048 + lane * 8;
    }

    f32x4 acc[4][4];
    #pragma unroll
    for (int mt = 0; mt < 4; ++mt)
        #pragma unroll
        for (int nt = 0; nt < 4; ++nt) acc[mt][nt] = (f32x4){0.f, 0.f, 0.f, 0.f};

    __syncthreads();   // weights ready

    bf16x8 a_cur[4], a_nxt[4];
    #pragma unroll
    for (int mt = 0; mt < 4; ++mt) a_cur[mt] = *(const bf16x8*)(Hself + aoff[mt]);

    #pragma unroll
    for (int ks = 0; ks < 8; ++ks) {
        if (ks < 7) {
            const int ks1 = ks + 1;
            const int col = (ks1 & 3) * 512;    // blocked k-slice offset (shorts)
            const unsigned short* __restrict__ base = (ks1 < 4) ? Hself : Hagg;  // compile-time
            #pragma unroll
            for (int mt = 0; mt < 4; ++mt)
                a_nxt[mt] = *(const bf16x8*)(base + aoff[mt] + col);
        }
        const int c = ks * 4 + l4;
        bf16x8 b[4];                            // shared across all mt (4 LDS reads/ks)
        #pragma unroll
        for (int nt = 0; nt < 4; ++nt) {
            int n = nbase + nt * 16 + l15;
            b[nt] = *(const bf16x8*)(sW + n * 256 + (c & 24) * 8 + (((c ^ n) & 7) * 8));
        }
        #pragma unroll
        for (int mt = 0; mt < 4; ++mt) {
            acc[mt][0] = __builtin_amdgcn_mfma_f32_16x16x32_bf16(a_cur[mt], b[0], acc[mt][0], 0, 0, 0);
            acc[mt][1] = __builtin_amdgcn_mfma_f32_16x16x32_bf16(a_cur[mt], b[1], acc[mt][1], 0, 0, 0);
            acc[mt][2] = __builtin_amdgcn_mfma_f32_16x16x32_bf16(a_cur[mt], b[2], acc[mt][2], 0, 0, 0);
            acc[mt][3] = __builtin_amdgcn_mfma_f32_16x16x32_bf16(a_cur[mt], b[3], acc[mt][3], 0, 0, 0);
        }
        #pragma unroll
        for (int mt = 0; mt < 4; ++mt) a_cur[mt] = a_nxt[mt];
    }

    // epilogue (no barrier; wave-local rows, all A-reads already consumed)
    #pragma unroll
    for (int nt = 0; nt < 4; ++nt) {
        int col = nbase + nt * 16 + l15;
        float bj = bias[col];
        #pragma unroll
        for (int mt = 0; mt < 4; ++mt) {
            #pragma unroll
            for (int r = 0; r < 4; ++r) {
                int grow = row0 + mbase + mt * 16 + l4 * 4 + r;
                if (grow < M) {
                    float v = fmaxf(acc[mt][nt][r] + bj, 0.f);
                    if (outF) {
                        outF[(size_t)grow * 128 + col] = v;          // final: row-major f32
                    } else {
                        unsigned short bv = f2bf(v);
                        outR[(size_t)grow * 128 + col] = bv;         // row-major bf16
                        int bo = (grow >> 4) * 2048 + (col >> 5) * 512
                               + ((col >> 3) & 3) * 128 + (grow & 15) * 8 + (col & 7);
                        outB[bo] = bv;                               // blocked bf16
                    }
                }
            }
        }
    }
}

extern "C" void kernel_launch(void* const* d_in, const int* in_sizes, int n_in,
                              void* d_out, int out_size, void* d_ws, size_t ws_size,
                              hipStream_t stream) {
    const float* x_src        = (const float*)d_in[0];
    const float* x_dst        = (const float*)d_in[1];
    const int*   e_src        = (const int*)d_in[2];
    const int*   e_dst        = (const int*)d_in[3];
    const float* W_ship_self  = (const float*)d_in[4];
    const float* W_ship_neigh = (const float*)d_in[5];
    const float* b_ship       = (const float*)d_in[6];
    const float* W_rev_self   = (const float*)d_in[7];
    const float* W_rev_neigh  = (const float*)d_in[8];
    const float* b_rev        = (const float*)d_in[9];
    float* out = (float*)d_out;

    char* ws = (char*)d_ws;
    size_t off = 0;
    auto alloc = [&](size_t bytes) {
        char* p = ws + off;
        off = (off + bytes + 255) & ~(size_t)255;
        return p;
    };
    unsigned short* xs_row = (unsigned short*)alloc((size_t)NN * DD * 2);   // h_s row-major
    unsigned short* xd_row = (unsigned short*)alloc((size_t)NN * DD * 2);   // h_d row-major
    unsigned short* xs_blk = (unsigned short*)alloc((size_t)NN * DD * 2);   // h_s blocked
    unsigned short* xd_blk = (unsigned short*)alloc((size_t)NN * DD * 2);   // h_d blocked
    unsigned short* agg1   = (unsigned short*)alloc((size_t)NN * DD * 2);   // blocked
    unsigned short* agg2   = (unsigned short*)alloc((size_t)NN * DD * 2);   // blocked
    unsigned short* Wss_bf = (unsigned short*)alloc(2 * DD * DD * 2);
    unsigned short* Wsn_bf = (unsigned short*)alloc(2 * DD * DD * 2);
    unsigned short* Wrs_bf = (unsigned short*)alloc(2 * DD * DD * 2);
    unsigned short* Wrn_bf = (unsigned short*)alloc(2 * DD * DD * 2);
    int* gcnt = (int*)alloc(2 * 256 * 4);
    int* csr_base = (int*)alloc(2 * 200 * 4);
    unsigned* recbin = (unsigned*)alloc((size_t)2 * NBKT * SLACK * 4);
    int* rp_dst = (int*)alloc((NN + 1) * 4);
    int* rp_src = (int*)alloc((NN + 1) * 4);
    float* inv_dst = (float*)alloc(NN * 4);
    float* inv_src = (float*)alloc(NN * 4);
    int* csr_dst = (int*)alloc(EDGES * 4);
    int* csr_src = (int*)alloc(EDGES * 4);
    (void)ws_size; (void)in_sizes; (void)n_in; (void)out_size;

    hipMemsetAsync(gcnt, 0, 2 * 256 * 4, stream);

    f2bx_kernel<<<dim3(NN * 16 / 256, 2), 256, 0, stream>>>(
        x_src, x_dst, xs_row, xs_blk, xd_row, xd_blk);
    f2bw_kernel<<<dim3(32, 4), 256, 0, stream>>>(W_ship_self, W_ship_neigh, W_rev_self, W_rev_neigh,
                                                 Wss_bf, Wsn_bf, Wrs_bf, Wrn_bf);

    bin_scatter_kernel<<<dim3(BPD, 2), 256, 0, stream>>>(e_src, e_dst, gcnt, recbin);
    bucket_scan_kernel<<<1, 256, 0, stream>>>(gcnt, csr_base);
    fine_place_kernel<<<dim3(NBKT, 2), 256, 0, stream>>>(recbin, gcnt, csr_base,
        rp_dst, rp_src, inv_dst, inv_src, csr_dst, csr_src);

    float* out_s = out;                       // h_s final
    float* out_d = out + (size_t)NN * DD;     // h_d final
    const int gemm_grid = (NN + 255) / 256;   // 391 (M=256 per block)
    const int agg_grid  = NN * 16 / 256;      // 6250 (16 lanes per node; block = one tile)

    for (int l = 0; l < 2; ++l) {
        // dir0: agg1 = mean h_s by dst ; dir1: agg2 = mean h_d by src
        // (gather from ROW-major h; layer-0 GEMM rewrote xs/xd in place with h1)
        aggregate5_kernel<<<dim3(agg_grid, 2), 256, 0, stream>>>(
            xs_row, rp_dst, csr_dst, agg1,
            xd_row, rp_src, csr_src, agg2);
        // dir0: new_d = relu(h_d@Wss^T + agg1@Wsn^T + b_ship)
        // dir1: new_s = relu(h_s@Wrs^T + agg2@Wrn^T + b_rev)
        // layer 0: write h1 into xd_*/xs_* IN PLACE (both layouts); layer 1: f32 out.
        mfma_gemm9_kernel<<<dim3(gemm_grid, 2), 512, 0, stream>>>(
            xd_blk, agg1, Wss_bf + l * DD * DD, Wsn_bf + l * DD * DD, b_ship + l * DD,
            l ? out_d : nullptr, xd_row, xd_blk,
            xs_blk, agg2, Wrs_bf + l * DD * DD, Wrn_bf + l * DD * DD, b_rev + l * DD,
            l ? out_s : nullptr, xs_row, xs_blk,
            NN);
    }
}

// Round 6
// 410.405 us; speedup vs baseline: 1.9560x; 1.0235x over previous
//
#include <hip/hip_runtime.h>
#include <hip/hip_bf16.h>

#define NN 100000      // N_SRC == N_DST
#define EDGES 500000
#define DD 128
#define NBKT 196       // buckets of 512 nodes (100000/512 -> 196)
#define SLACK 3584     // per-bucket record capacity (mean 2551, sigma ~50 -> 20 sigma margin)
#define CHUNK 2048     // edges per bin role-block (21KB LDS -> 7 blocks/CU in fused prep)
#define BPD ((EDGES + CHUNK - 1) / CHUNK)   // 245
#define XBLK (NN * 16 / 256)                // 6250 f2bx role-blocks per matrix

// ---- dual layouts for bf16 H matrices ----
// ROW-major  (aggregate gather source): h[row*128 + col]
// BLOCKED    (GEMM A source): offset(row,col) = (row>>4)*2048 + (col>>5)*512
//   + ((col>>3)&3)*128 + (row&15)*8 + (col&7)  -> an MFMA A-fragment load is
//   base + rt*2048 + ks*512 + lane*8 == 64 lanes x 16B CONTIGUOUS (8 full lines).

typedef short bf16x8 __attribute__((ext_vector_type(8)));
typedef float f32x4  __attribute__((ext_vector_type(4)));
typedef float f32x2  __attribute__((ext_vector_type(2)));

__device__ __forceinline__ unsigned short f2bf(float f) {
    unsigned u = __float_as_uint(f);
    u += 0x7fffu + ((u >> 16) & 1u);      // round-to-nearest-even (no NaN inputs here)
    return (unsigned short)(u >> 16);
}

// ---------------- fused prep: edge binning + fp32->bf16 dual-layout convert ------
// Role-split flat grid: blocks [0, 2*BPD) run the LDS-multisplit edge binning;
// blocks [2*BPD, 2*BPD + 2*XBLK) run the x conversion (independent work, one
// launch instead of two -> one less serial dispatch gap).
__global__ __launch_bounds__(256) void prep_kernel(
    const float* __restrict__ x_src, const float* __restrict__ x_dst,
    unsigned short* __restrict__ xsR, unsigned short* __restrict__ xsB,
    unsigned short* __restrict__ xdR, unsigned short* __restrict__ xdB,
    const int* __restrict__ e_src, const int* __restrict__ e_dst,
    int* __restrict__ gcnt,              // [2*256], zero-initialized
    unsigned* __restrict__ recbin)       // [2 * NBKT * SLACK]
{
    const int bid = blockIdx.x;
    const int t = threadIdx.x;

    __shared__ int hist[256];
    __shared__ int lbase[256];
    __shared__ int lofs[256];
    __shared__ int scanA[256], scanB[256];
    __shared__ int laddr[CHUNK];
    __shared__ unsigned lrec[CHUNK];

    if (bid < 2 * BPD) {
        // ---- bin role ----
        const int dir = (bid >= BPD) ? 1 : 0;
        const int c0 = (dir ? bid - BPD : bid) * CHUNK;
        const int nvalid = min(CHUNK, EDGES - c0);
        const int* __restrict__ TGT = dir ? e_src : e_dst;
        const int* __restrict__ PAY = dir ? e_dst : e_src;

        hist[t] = 0;
        __syncthreads();

        int myb[8], myslot[8];
        unsigned myrec[8];
        #pragma unroll
        for (int j = 0; j < 8; ++j) {
            int e = c0 + j * 256 + t;
            myb[j] = -1;
            if (e < EDGES) {
                int tgt = TGT[e], pay = PAY[e];
                int b = tgt >> 9;
                myb[j] = b;
                myrec[j] = ((unsigned)pay << 9) | (unsigned)(tgt & 511);
                myslot[j] = atomicAdd(&hist[b], 1);
            }
        }
        __syncthreads();
        int cnt = hist[t];
        lbase[t] = (cnt > 0) ? atomicAdd(&gcnt[dir * 256 + t], cnt) : 0;
        scanA[t] = cnt;
        __syncthreads();
        int* pa = scanA; int* pb = scanB;
        for (int d = 1; d < 256; d <<= 1) {
            pb[t] = pa[t] + (t >= d ? pa[t - d] : 0);
            __syncthreads();
            int* tmp = pa; pa = pb; pb = tmp;
        }
        lofs[t] = pa[t] - cnt;                 // exclusive scan
        __syncthreads();
        #pragma unroll
        for (int j = 0; j < 8; ++j) {
            if (myb[j] >= 0) {
                int b = myb[j];
                int pos = lofs[b] + myslot[j];
                int g = lbase[b] + myslot[j];
                lrec[pos] = myrec[j];
                laddr[pos] = (g < SLACK) ? (b * SLACK + g) : -1;   // overflow guard
            }
        }
        __syncthreads();
        unsigned* __restrict__ out = recbin + (size_t)dir * NBKT * SLACK;
        #pragma unroll
        for (int j = 0; j < 8; ++j) {
            int i = j * 256 + t;
            if (i < nvalid) {
                int a = laddr[i];
                if (a >= 0) out[a] = lrec[i];  // bucket-sorted -> near-coalesced runs
            }
        }
    } else {
        // ---- f2bx role: one 16-node tile per block, writes BOTH layouts ----
        int q = bid - 2 * BPD;                 // 0 .. 2*XBLK-1
        const float* in; unsigned short* outR; unsigned short* outB;
        if (q < XBLK) { in = x_src; outR = xsR; outB = xsB; }
        else          { in = x_dst; outR = xdR; outB = xdB; q -= XBLK; }
        int tt = q * 256 + t;                  // tt < NN*16
        int row = tt >> 4, sl = tt & 15;
        const float4* src = (const float4*)in + row * 32 + sl * 2;
        float4 v0 = src[0], v1 = src[1];
        uint4 o;
        o.x = (unsigned)f2bf(v0.x) | ((unsigned)f2bf(v0.y) << 16);
        o.y = (unsigned)f2bf(v0.z) | ((unsigned)f2bf(v0.w) << 16);
        o.z = (unsigned)f2bf(v1.x) | ((unsigned)f2bf(v1.y) << 16);
        o.w = (unsigned)f2bf(v1.z) | ((unsigned)f2bf(v1.w) << 16);
        *(uint4*)(outR + row * 128 + sl * 8) = o;        // row-major
        int boff = (row >> 4) * 2048 + (sl >> 2) * 512 + (sl & 3) * 128 + (row & 15) * 8;
        *(uint4*)(outB + boff) = o;                      // blocked (whole-tile writes)
    }
}

// ---------------- fine placement (bucket-count scan fused in) ----------------
// Each block re-derives its csr base from a 196-entry LDS scan (~1us of work)
// -- replaces the serial bucket_scan dispatch. inv[] dropped (aggregate
// recomputes 1/deg from rp).
__global__ __launch_bounds__(256) void fine_place2_kernel(
    const unsigned* __restrict__ recbin, const int* __restrict__ gcnt,
    int* __restrict__ rp_dst, int* __restrict__ rp_src,
    int* __restrict__ csr_dst, int* __restrict__ csr_src)
{
    const int dir = blockIdx.y;
    const int bkt = blockIdx.x;
    const int t = threadIdx.x;
    int* __restrict__ rp  = dir ? rp_src  : rp_dst;
    int* __restrict__ csr = dir ? csr_src : csr_dst;
    const unsigned* __restrict__ recs = recbin + ((size_t)dir * NBKT + bkt) * SLACK;
    const int cnt = min(gcnt[dir * 256 + bkt], SLACK);
    const int n0 = bkt * 512;

    __shared__ int deg[512];
    __shared__ int sA[512], sB[512];
    __shared__ int cur[512];

    // phase 0: scan of per-bucket counts -> this bucket's csr base + total
    sA[t] = (t < NBKT) ? min(gcnt[dir * 256 + t], SLACK) : 0;
    __syncthreads();
    {
        int* pa = sA; int* pb = sB;
        for (int d = 1; d < 256; d <<= 1) {
            pb[t] = pa[t] + (t >= d ? pa[t - d] : 0);
            __syncthreads();
            int* tmp = pa; pa = pb; pb = tmp;
        }
        // after 8 rounds result is back in sA
    }
    const int cbase = sA[bkt] - cnt;           // exclusive prefix at bkt
    const int total = sA[255];
    __syncthreads();                           // before reusing sA/sB

    deg[t] = 0; deg[t + 256] = 0;
    __syncthreads();
    for (int i = t; i < cnt; i += 256)
        atomicAdd(&deg[recs[i] & 511u], 1);
    __syncthreads();
    sA[t] = deg[t]; sA[t + 256] = deg[t + 256];
    __syncthreads();
    int* pa = sA; int* pb = sB;
    for (int d = 1; d < 512; d <<= 1) {
        pb[t]       = pa[t]       + (t >= d           ? pa[t - d]       : 0);
        pb[t + 256] = pa[t + 256] + ((t + 256) >= d   ? pa[t + 256 - d] : 0);
        __syncthreads();
        int* tmp = pa; pa = pb; pb = tmp;
    }
    #pragma unroll
    for (int k = 0; k < 2; ++k) {
        int i = t + k * 256;
        int off = pa[i] - deg[i];          // exclusive
        cur[i] = off;
        int node = n0 + i;
        if (node < NN) rp[node] = cbase + off;   // coalesced rp write
    }
    if (bkt == NBKT - 1 && t == 0) rp[NN] = total;
    __syncthreads();
    for (int i = t; i < cnt; i += 256) {
        unsigned r = recs[i];
        int p = atomicAdd(&cur[r & 511u], 1);
        csr[cbase + p] = (int)(r >> 9);    // scattered 4B stores within ~10KB window
    }
}

// ---------------- mean aggregation: ROW-major gather, BLOCKED store ----------------
// wave = 4 nodes, 16 lanes per node, 16B per lane; all csr + all row gathers
// issued flat (3 serialized memory phases per wave regardless of degree).
__global__ __launch_bounds__(256) void aggregate5_kernel(
    const unsigned short* __restrict__ h0, const int* __restrict__ rp0,
    const int* __restrict__ csr0, unsigned short* __restrict__ ag0,
    const unsigned short* __restrict__ h1, const int* __restrict__ rp1,
    const int* __restrict__ csr1, unsigned short* __restrict__ ag1)
{
    const int dir = blockIdx.y;
    const unsigned short* __restrict__ h = dir ? h1 : h0;
    const int* __restrict__ rp   = dir ? rp1 : rp0;
    const int* __restrict__ csr  = dir ? csr1 : csr0;
    unsigned short* __restrict__ agg = dir ? ag1 : ag0;

    const int t  = blockIdx.x * 256 + threadIdx.x;
    const int g  = t >> 4;          // node id (grid sized exactly: NN*16 threads)
    const int sl = t & 15;          // 16B slice of the 256B row

    const int beg = rp[g], end = rp[g + 1];
    const unsigned short* __restrict__ hp = h + sl * 8;   // row-major gather base

    f32x2 acc[4];
    #pragma unroll
    for (int k = 0; k < 4; ++k) acc[k] = (f32x2){0.f, 0.f};

    // phase 2: all csr indices at once (predicated, independent)
    int cidx[8];
    #pragma unroll
    for (int j = 0; j < 8; ++j)
        cidx[j] = (beg + j < end) ? csr[beg + j] : -1;

    // phase 3: all row gathers at once (independent dwordx4 loads)
    bf16x8 v[8];
    #pragma unroll
    for (int j = 0; j < 8; ++j)
        if (cidx[j] >= 0)
            v[j] = *(const bf16x8*)(hp + (size_t)cidx[j] * DD);

    #pragma unroll
    for (int j = 0; j < 8; ++j) {
        if (cidx[j] >= 0) {
            const unsigned* pu = (const unsigned*)&v[j];
            #pragma unroll
            for (int k = 0; k < 4; ++k) {
                unsigned u = pu[k];
                acc[k] += (f32x2){__uint_as_float(u << 16),
                                  __uint_as_float(u & 0xffff0000u)};
            }
        }
    }

    // rare tail: deg > 8 (~7% of nodes)
    for (int i = beg + 8; i < end; ++i) {
        int c = csr[i];
        bf16x8 wv = *(const bf16x8*)(hp + (size_t)c * DD);
        const unsigned* pu = (const unsigned*)&wv;
        #pragma unroll
        for (int k = 0; k < 4; ++k) {
            unsigned u = pu[k];
            acc[k] += (f32x2){__uint_as_float(u << 16),
                              __uint_as_float(u & 0xffff0000u)};
        }
    }

    const float sc = 1.0f / (float)max(end - beg, 1);
    uint4 ov;
    ov.x = (unsigned)f2bf(acc[0].x * sc) | ((unsigned)f2bf(acc[0].y * sc) << 16);
    ov.y = (unsigned)f2bf(acc[1].x * sc) | ((unsigned)f2bf(acc[1].y * sc) << 16);
    ov.z = (unsigned)f2bf(acc[2].x * sc) | ((unsigned)f2bf(acc[2].y * sc) << 16);
    ov.w = (unsigned)f2bf(acc[3].x * sc) | ((unsigned)f2bf(acc[3].y * sc) << 16);
    int boff = (g >> 4) * 2048 + (sl >> 2) * 512 + (sl & 3) * 128 + (g & 15) * 8;
    *(uint4*)(agg + boff) = ov;                          // blocked store
}

// ---------------- MFMA GEMM v10: blocked-A + in-kernel f32 weight staging --------
// out = relu([Hself|Hagg] @ [Wself|Wneigh]^T + b), bf16 in, fp32 acc.
// vs v9: weights staged DIRECTLY from f32 (conversion in the stage loop;
// 128KB f32 per block is L2/L3-resident across 782 blocks -> ~free) -- kills
// the f2bw dispatch; first A-fragment loads issued BEFORE the staging loop so
// their HBM latency hides under staging. Layer 0 (outF==null) writes both
// row-major and blocked bf16 IN PLACE (wave-local rows; reads all consumed by
// MFMA before epilogue stores; tail-clamp reads discarded). Layer 1: f32 out.
__global__ __launch_bounds__(512, 4) void mfma_gemm10_kernel(
    const unsigned short* __restrict__ Hs0, const unsigned short* __restrict__ Ha0,
    const float* __restrict__ Ws0, const float* __restrict__ Wn0,
    const float* __restrict__ bias0, float* __restrict__ outF0,
    unsigned short* __restrict__ outR0, unsigned short* __restrict__ outB0,
    const unsigned short* __restrict__ Hs1, const unsigned short* __restrict__ Ha1,
    const float* __restrict__ Ws1, const float* __restrict__ Wn1,
    const float* __restrict__ bias1, float* __restrict__ outF1,
    unsigned short* __restrict__ outR1, unsigned short* __restrict__ outB1,
    int M)
{
    const int dir = blockIdx.y;
    const unsigned short* __restrict__ Hself = dir ? Hs1 : Hs0;
    const unsigned short* __restrict__ Hagg  = dir ? Ha1 : Ha0;
    const float* __restrict__ Wself = dir ? Ws1 : Ws0;
    const float* __restrict__ Wneigh= dir ? Wn1 : Wn0;
    const float* __restrict__ bias = dir ? bias1 : bias0;
    float* __restrict__ outF = dir ? outF1 : outF0;
    unsigned short* __restrict__ outR = dir ? outR1 : outR0;
    unsigned short* __restrict__ outB = dir ? outB1 : outB0;

    __shared__ __align__(16) unsigned short sW[128 * 256];  // fused weights, swizzled (64 KB)
    const int tid  = threadIdx.x;
    const int lane = tid & 63;
    const int w    = tid >> 6;                // 0..7
    const int row0 = blockIdx.x * 256;

    const int mbase = (w >> 1) * 64;          // 0,64,128,192
    const int nbase = (w & 1) * 64;           // 0,64
    const int l15 = lane & 15;
    const int l4  = lane >> 4;
    const int MT  = M >> 4;                   // 6250 row-tiles

    // blocked A offsets (shorts): rt*2048 + lane*8 ; k-slice adds ks*512
    int aoff[4];
    #pragma unroll
    for (int mt = 0; mt < 4; ++mt) {
        int rt = ((row0 + mbase) >> 4) + mt;
        if (rt >= MT) rt = MT - 1;            // tail clamp (valid data, results discarded)
        aoff[mt] = rt * 2048 + lane * 8;
    }

    // first A-fragments issued BEFORE staging: HBM latency hides under the stage loop
    bf16x8 a_cur[4], a_nxt[4];
    #pragma unroll
    for (int mt = 0; mt < 4; ++mt) a_cur[mt] = *(const bf16x8*)(Hself + aoff[mt]);

    #pragma unroll
    for (int i = 0; i < 8; ++i) {             // stage fused weights from f32 (convert+swizzle)
        int q = i * 512 + tid;                // 0..4095
        int n = q >> 5, c = q & 31;
        const float* src = (c < 16) ? (Wself  + n * 128 + (c & 15) * 8)
                                    : (Wneigh + n * 128 + (c - 16) * 8);
        float4 v0 = *(const float4*)src;
        float4 v1 = *(const float4*)(src + 4);
        uint4 o;
        o.x = (unsigned)f2bf(v0.x) | ((unsigned)f2bf(v0.y) << 16);
        o.y = (unsigned)f2bf(v0.z) | ((unsigned)f2bf(v0.w) << 16);
        o.z = (unsigned)f2bf(v1.x) | ((unsigned)f2bf(v1.y) << 16);
        o.w = (unsigned)f2bf(v1.z) | ((unsigned)f2bf(v1.w) << 16);
        int d = n * 256 + (c & 24) * 8 + (((c ^ n) & 7) * 8);
        *(uint4*)(sW + d) = o;
    }

    f32x4 acc[4][4];
    #pragma unroll
    for (int mt = 0; mt < 4; ++mt)
        #pragma unroll
        for (int nt = 0; nt < 4; ++nt) acc[mt][nt] = (f32x4){0.f, 0.f, 0.f, 0.f};

    __syncthreads();   // weights ready

    #pragma unroll
    for (int ks = 0; ks < 8; ++ks) {
        if (ks < 7) {
            const int ks1 = ks + 1;
            const int col = (ks1 & 3) * 512;    // blocked k-slice offset (shorts)
            const unsigned short* __restrict__ base = (ks1 < 4) ? Hself : Hagg;  // compile-time
            #pragma unroll
            for (int mt = 0; mt < 4; ++mt)
                a_nxt[mt] = *(const bf16x8*)(base + aoff[mt] + col);
        }
        const int c = ks * 4 + l4;
        bf16x8 b[4];                            // shared across all mt (4 LDS reads/ks)
        #pragma unroll
        for (int nt = 0; nt < 4; ++nt) {
            int n = nbase + nt * 16 + l15;
            b[nt] = *(const bf16x8*)(sW + n * 256 + (c & 24) * 8 + (((c ^ n) & 7) * 8));
        }
        #pragma unroll
        for (int mt = 0; mt < 4; ++mt) {
            acc[mt][0] = __builtin_amdgcn_mfma_f32_16x16x32_bf16(a_cur[mt], b[0], acc[mt][0], 0, 0, 0);
            acc[mt][1] = __builtin_amdgcn_mfma_f32_16x16x32_bf16(a_cur[mt], b[1], acc[mt][1], 0, 0, 0);
            acc[mt][2] = __builtin_amdgcn_mfma_f32_16x16x32_bf16(a_cur[mt], b[2], acc[mt][2], 0, 0, 0);
            acc[mt][3] = __builtin_amdgcn_mfma_f32_16x16x32_bf16(a_cur[mt], b[3], acc[mt][3], 0, 0, 0);
        }
        #pragma unroll
        for (int mt = 0; mt < 4; ++mt) a_cur[mt] = a_nxt[mt];
    }

    // epilogue (no barrier; wave-local rows, all A-reads already consumed)
    #pragma unroll
    for (int nt = 0; nt < 4; ++nt) {
        int col = nbase + nt * 16 + l15;
        float bj = bias[col];
        #pragma unroll
        for (int mt = 0; mt < 4; ++mt) {
            #pragma unroll
            for (int r = 0; r < 4; ++r) {
                int grow = row0 + mbase + mt * 16 + l4 * 4 + r;
                if (grow < M) {
                    float v = fmaxf(acc[mt][nt][r] + bj, 0.f);
                    if (outF) {
                        outF[(size_t)grow * 128 + col] = v;          // final: row-major f32
                    } else {
                        unsigned short bv = f2bf(v);
                        outR[(size_t)grow * 128 + col] = bv;         // row-major bf16
                        int bo = (grow >> 4) * 2048 + (col >> 5) * 512
                               + ((col >> 3) & 3) * 128 + (grow & 15) * 8 + (col & 7);
                        outB[bo] = bv;                               // blocked bf16
                    }
                }
            }
        }
    }
}

extern "C" void kernel_launch(void* const* d_in, const int* in_sizes, int n_in,
                              void* d_out, int out_size, void* d_ws, size_t ws_size,
                              hipStream_t stream) {
    const float* x_src        = (const float*)d_in[0];
    const float* x_dst        = (const float*)d_in[1];
    const int*   e_src        = (const int*)d_in[2];
    const int*   e_dst        = (const int*)d_in[3];
    const float* W_ship_self  = (const float*)d_in[4];
    const float* W_ship_neigh = (const float*)d_in[5];
    const float* b_ship       = (const float*)d_in[6];
    const float* W_rev_self   = (const float*)d_in[7];
    const float* W_rev_neigh  = (const float*)d_in[8];
    const float* b_rev        = (const float*)d_in[9];
    float* out = (float*)d_out;

    char* ws = (char*)d_ws;
    size_t off = 0;
    auto alloc = [&](size_t bytes) {
        char* p = ws + off;
        off = (off + bytes + 255) & ~(size_t)255;
        return p;
    };
    unsigned short* xs_row = (unsigned short*)alloc((size_t)NN * DD * 2);   // h_s row-major
    unsigned short* xd_row = (unsigned short*)alloc((size_t)NN * DD * 2);   // h_d row-major
    unsigned short* xs_blk = (unsigned short*)alloc((size_t)NN * DD * 2);   // h_s blocked
    unsigned short* xd_blk = (unsigned short*)alloc((size_t)NN * DD * 2);   // h_d blocked
    unsigned short* agg1   = (unsigned short*)alloc((size_t)NN * DD * 2);   // blocked
    unsigned short* agg2   = (unsigned short*)alloc((size_t)NN * DD * 2);   // blocked
    int* gcnt = (int*)alloc(2 * 256 * 4);
    unsigned* recbin = (unsigned*)alloc((size_t)2 * NBKT * SLACK * 4);
    int* rp_dst = (int*)alloc((NN + 1) * 4);
    int* rp_src = (int*)alloc((NN + 1) * 4);
    int* csr_dst = (int*)alloc(EDGES * 4);
    int* csr_src = (int*)alloc(EDGES * 4);
    (void)ws_size; (void)in_sizes; (void)n_in; (void)out_size;

    hipMemsetAsync(gcnt, 0, 2 * 256 * 4, stream);

    // fused binning + conversion (role-split flat grid; bin blocks first)
    prep_kernel<<<2 * BPD + 2 * XBLK, 256, 0, stream>>>(
        x_src, x_dst, xs_row, xs_blk, xd_row, xd_blk,
        e_src, e_dst, gcnt, recbin);

    fine_place2_kernel<<<dim3(NBKT, 2), 256, 0, stream>>>(
        recbin, gcnt, rp_dst, rp_src, csr_dst, csr_src);

    float* out_s = out;                       // h_s final
    float* out_d = out + (size_t)NN * DD;     // h_d final
    const int gemm_grid = (NN + 255) / 256;   // 391 (M=256 per block)
    const int agg_grid  = NN * 16 / 256;      // 6250 (16 lanes per node; block = one tile)

    for (int l = 0; l < 2; ++l) {
        // dir0: agg1 = mean h_s by dst ; dir1: agg2 = mean h_d by src
        // (gather from ROW-major h; layer-0 GEMM rewrote xs/xd in place)
        aggregate5_kernel<<<dim3(agg_grid, 2), 256, 0, stream>>>(
            xs_row, rp_dst, csr_dst, agg1,
            xd_row, rp_src, csr_src, agg2);
        // dir0: new_d = relu(h_d@Wss^T + agg1@Wsn^T + b_ship)
        // dir1: new_s = relu(h_s@Wrs^T + agg2@Wrn^T + b_rev)
        // layer 0: write h1 into xd_*/xs_* IN PLACE (both layouts); layer 1: f32 out.
        mfma_gemm10_kernel<<<dim3(gemm_grid, 2), 512, 0, stream>>>(
            xd_blk, agg1, W_ship_self + l * DD * DD, W_ship_neigh + l * DD * DD, b_ship + l * DD,
            l ? out_d : nullptr, xd_row, xd_blk,
            xs_blk, agg2, W_rev_self + l * DD * DD, W_rev_neigh + l * DD * DD, b_rev + l * DD,
            l ? out_s : nullptr, xs_row, xs_blk,
            NN);
    }
}